// Round 1
// baseline (2005.281 us; speedup 1.0000x reference)
//
#include <hip/hip_runtime.h>
#include <hip/hip_bf16.h>
#include <math.h>

#define B_ 8
#define S_ 1024
#define E_ 1024
#define H_ 16
#define HD_ 64
#define F_ 4096
#define M_ (B_ * S_)   // 8192

typedef float f32x4 __attribute__((ext_vector_type(4)));
typedef short short8 __attribute__((ext_vector_type(8)));
typedef unsigned short ushort_t;

__device__ inline unsigned short f2bf(float x) {
    union { float f; unsigned int u; } v; v.f = x;
    unsigned int r = (v.u + 0x7fffu + ((v.u >> 16) & 1u)) >> 16;
    return (unsigned short)r;
}
__device__ inline float bf2f(unsigned short u) {
    union { unsigned int u; float f; } v; v.u = ((unsigned int)u) << 16;
    return v.f;
}

#define AS1 __attribute__((address_space(1)))
#define AS3 __attribute__((address_space(3)))
__device__ inline void gload_lds16(const void* g, void* l) {
    __builtin_amdgcn_global_load_lds((const AS1 unsigned int*)(g),
                                     (AS3 unsigned int*)(l), 16, 0, 0);
}

// ---------------- cast x fp32 -> bf16 ----------------
__global__ __launch_bounds__(256) void cast_f32_bf16(const float* __restrict__ in,
                                                     unsigned short* __restrict__ out) {
    int i = (blockIdx.x * 256 + threadIdx.x) * 4;
    float4 v = *(const float4*)(in + i);
    ushort4 o;
    o.x = f2bf(v.x); o.y = f2bf(v.y); o.z = f2bf(v.z); o.w = f2bf(v.w);
    *(ushort4*)(out + i) = o;
}

// ---------------- transpose+cast weight: in[K,N] f32 -> out[N,K] bf16 ----------------
__global__ __launch_bounds__(256) void transpose_cast(const float* __restrict__ in,
                                                      unsigned short* __restrict__ out,
                                                      int K, int N) {
    __shared__ float tile[32][33];
    int n0 = blockIdx.x * 32, k0 = blockIdx.y * 32;
    int tc = threadIdx.x & 31, tr = threadIdx.x >> 5;  // tr 0..7
    for (int i = 0; i < 4; ++i) {
        int k = k0 + tr + i * 8;
        tile[tr + i * 8][tc] = in[(size_t)k * N + n0 + tc];
    }
    __syncthreads();
    for (int i = 0; i < 4; ++i) {
        int n = n0 + tr + i * 8;
        out[(size_t)n * K + k0 + tc] = f2bf(tile[tc][tr + i * 8]);
    }
}

// ---------------- GEMM: C[M,N] = A[M,K](bf16) @ Bt[N,K]^T(bf16) + bias, epilogues ----------------
// EPI 0: qkv  -> bias, scale cols<1024 by 1/8, store bf16
// EPI 1: gelu -> bias, exact gelu, store bf16
// EPI 2: res  -> bias + res[row*N+col], store fp32
#define BM 128
#define BN 128
#define BK 32
template <int EPI>
__global__ __launch_bounds__(256) void gemm_bt(const unsigned short* __restrict__ A,
                                               const unsigned short* __restrict__ Bt,
                                               const float* __restrict__ bias,
                                               const float* __restrict__ res,
                                               unsigned short* __restrict__ Cb,
                                               float* __restrict__ Cf,
                                               int M, int N, int K) {
    __shared__ unsigned short lA[BM * BK];
    __shared__ unsigned short lB[BN * BK];
    int row0 = blockIdx.y * BM, col0 = blockIdx.x * BN;
    int t = threadIdx.x;
    int lane = t & 63, w = t >> 6;
    int wr = w >> 1, wc = w & 1;
    int qa = lane >> 4, ml = lane & 15;

    f32x4 acc[4][4] = {};
    const unsigned short* Aptr = A + (size_t)row0 * K;
    const unsigned short* Bptr = Bt + (size_t)col0 * K;

    for (int k0 = 0; k0 < K; k0 += BK) {
        __syncthreads();
        for (int i = 0; i < 2; ++i) {
            int c = t + i * 256;
            int r = c >> 2, kc = c & 3;
            gload_lds16(Aptr + (size_t)r * K + k0 + kc * 8, lA + c * 8);
            gload_lds16(Bptr + (size_t)r * K + k0 + kc * 8, lB + c * 8);
        }
        __syncthreads();
        short8 af[4], bf[4];
        for (int i = 0; i < 4; ++i)
            af[i] = *(const short8*)&lA[(wr * 64 + i * 16 + ml) * BK + qa * 8];
        for (int j = 0; j < 4; ++j)
            bf[j] = *(const short8*)&lB[(wc * 64 + j * 16 + ml) * BK + qa * 8];
        for (int i = 0; i < 4; ++i)
            for (int j = 0; j < 4; ++j)
                acc[i][j] = __builtin_amdgcn_mfma_f32_16x16x32_bf16(af[i], bf[j], acc[i][j], 0, 0, 0);
    }

    for (int i = 0; i < 4; ++i) {
        for (int j = 0; j < 4; ++j) {
            int col = col0 + wc * 64 + j * 16 + ml;
            float bv = bias[col];
            for (int r = 0; r < 4; ++r) {
                int row = row0 + wr * 64 + i * 16 + qa * 4 + r;
                float cv = acc[i][j][r] + bv;
                if (EPI == 0) {
                    if (col < 1024) cv *= 0.125f;
                    Cb[(size_t)row * N + col] = f2bf(cv);
                } else if (EPI == 1) {
                    cv = 0.5f * cv * (1.0f + erff(cv * 0.70710678118654752f));
                    Cb[(size_t)row * N + col] = f2bf(cv);
                } else {
                    cv += res[(size_t)row * N + col];
                    Cf[(size_t)row * N + col] = cv;
                }
            }
        }
    }
}

// ---------------- transpose v slice of qkv -> vT[b,h,d,s] ----------------
__global__ __launch_bounds__(256) void transpose_v(const unsigned short* __restrict__ qkv,
                                                   unsigned short* __restrict__ vT) {
    __shared__ unsigned short tile[64][72];
    int s0 = blockIdx.x * 64;
    int pair = blockIdx.y;
    int b = pair >> 4, h = pair & 15;
    int t = threadIdx.x;
    int r = t >> 2, c0 = (t & 3) * 16;
    const unsigned short* src = qkv + (size_t)(b * S_ + s0 + r) * 3072 + 2048 + h * 64 + c0;
    *(short8*)&tile[r][c0] = *(const short8*)src;
    *(short8*)&tile[r][c0 + 8] = *(const short8*)(src + 8);
    __syncthreads();
    int d = t >> 2, sc0 = (t & 3) * 16;
    unsigned short tmp[16];
    for (int i = 0; i < 16; ++i) tmp[i] = tile[sc0 + i][d];
    unsigned short* dst = vT + ((size_t)pair * 64 + d) * S_ + s0 + sc0;
    *(short8*)dst = *(const short8*)&tmp[0];
    *(short8*)(dst + 8) = *(const short8*)&tmp[8];
}

// ---------------- fused attention: scores -> softmax -> ctx, per (b,h,16 q rows) ----------------
__global__ __launch_bounds__(256) void attn_kernel(const unsigned short* __restrict__ qkv,
                                                   const unsigned short* __restrict__ vT,
                                                   const int* __restrict__ am,
                                                   const int* __restrict__ tt,
                                                   unsigned short* __restrict__ ctx) {
    __shared__ unsigned short sc[16 * 1032];  // padded row stride 1032
    __shared__ unsigned short qtile[16 * 64];
    __shared__ float lsum[16];
    int qb = blockIdx.x;
    int pair = blockIdx.y;
    int b = pair >> 4, h = pair & 15;
    int t = threadIdx.x, w = t >> 6, lane = t & 63;
    int qa = lane >> 4, ml = lane & 15;
    int q0 = qb * 16;

    {   // load q tile [16][64]
        int r = t >> 4, c4 = (t & 15) * 4;
        const unsigned short* src = qkv + (size_t)(b * S_ + q0 + r) * 3072 + h * 64 + c4;
        *(uint2*)&qtile[r * 64 + c4] = *(const uint2*)src;
    }
    __syncthreads();

    short8 aq0 = *(const short8*)&qtile[ml * 64 + qa * 8];
    short8 aq1 = *(const short8*)&qtile[ml * 64 + 32 + qa * 8];
    int amq[4];
    for (int r = 0; r < 4; ++r) amq[r] = am[b * S_ + q0 + qa * 4 + r];

    // score phase: wave w handles key tiles w, w+4, ...
    for (int tile = w; tile < 64; tile += 4) {
        int kk = tile * 16 + ml;
        const unsigned short* kp = qkv + (size_t)(b * S_ + kk) * 3072 + 1024 + h * 64 + qa * 8;
        short8 b0 = *(const short8*)kp;
        short8 b1 = *(const short8*)(kp + 32);
        f32x4 a = {};
        a = __builtin_amdgcn_mfma_f32_16x16x32_bf16(aq0, b0, a, 0, 0, 0);
        a = __builtin_amdgcn_mfma_f32_16x16x32_bf16(aq1, b1, a, 0, 0, 0);
        int amk = am[b * S_ + kk];
        int ttk = tt[b * S_ + kk];
        bool neg = (ttk == 1) || (amk == 0) || (kk == 0);
        for (int r = 0; r < 4; ++r) {
            float s = a[r] + ((amq[r] != 0 && amk != 0) ? 1.0f : 0.0f);
            if (neg) s = -1e30f;
            sc[(qa * 4 + r) * 1032 + tile * 16 + ml] = f2bf(s);
        }
    }
    __syncthreads();

    // softmax: 16 threads per row (contiguous within one wave)
    {
        int r = t >> 4, j = t & 15;
        float mx = -3e38f;
        for (int i = 0; i < 64; ++i) mx = fmaxf(mx, bf2f(sc[r * 1032 + j + 16 * i]));
        for (int o = 8; o >= 1; o >>= 1) mx = fmaxf(mx, __shfl_xor(mx, o, 16));
        float sum = 0.f;
        for (int i = 0; i < 64; ++i) {
            int idx = r * 1032 + j + 16 * i;
            float p = expf(bf2f(sc[idx]) - mx);
            sum += p;
            sc[idx] = f2bf(p);
        }
        for (int o = 8; o >= 1; o >>= 1) sum += __shfl_xor(sum, o, 16);
        if (j == 0) lsum[r] = sum;
    }
    __syncthreads();

    // ctx phase: wave w -> d-tile w (cols w*16 .. w*16+15)
    f32x4 a = {};
    const unsigned short* vtp = vT + ((size_t)pair * 64 + w * 16 + ml) * S_;
    for (int k0 = 0; k0 < S_; k0 += 32) {
        short8 ap = *(const short8*)&sc[ml * 1032 + k0 + qa * 8];
        short8 bp = *(const short8*)(vtp + k0 + qa * 8);
        a = __builtin_amdgcn_mfma_f32_16x16x32_bf16(ap, bp, a, 0, 0, 0);
    }
    for (int r = 0; r < 4; ++r) {
        int row = qa * 4 + r;
        float inv = 1.0f / lsum[row];
        ctx[(size_t)(b * S_ + q0 + row) * E_ + h * 64 + w * 16 + ml] = f2bf(a[r] * inv);
    }
}

// ---------------- row LayerNorm over E=1024 ----------------
template <int WRITE_BF16>
__global__ __launch_bounds__(256) void ln_kernel(const float* __restrict__ in,
                                                 const float* __restrict__ lw,
                                                 const float* __restrict__ lb,
                                                 float* __restrict__ outf,
                                                 unsigned short* __restrict__ outb) {
    int row = blockIdx.x;
    int t = threadIdx.x;
    const float* x = in + (size_t)row * E_;
    float4 v = ((const float4*)x)[t];
    float s = v.x + v.y + v.z + v.w;
    float sq = v.x * v.x + v.y * v.y + v.z * v.z + v.w * v.w;
    for (int o = 32; o >= 1; o >>= 1) {
        s += __shfl_xor(s, o, 64);
        sq += __shfl_xor(sq, o, 64);
    }
    __shared__ float red[8];
    if ((t & 63) == 0) { red[t >> 6] = s; red[4 + (t >> 6)] = sq; }
    __syncthreads();
    s = red[0] + red[1] + red[2] + red[3];
    sq = red[4] + red[5] + red[6] + red[7];
    float mu = s * (1.0f / E_);
    float var = sq * (1.0f / E_) - mu * mu;
    float rstd = rsqrtf(fmaxf(var, 0.0f) + 1e-12f);
    float4 wv = ((const float4*)lw)[t];
    float4 bv = ((const float4*)lb)[t];
    float4 o;
    o.x = (v.x - mu) * rstd * wv.x + bv.x;
    o.y = (v.y - mu) * rstd * wv.y + bv.y;
    o.z = (v.z - mu) * rstd * wv.z + bv.z;
    o.w = (v.w - mu) * rstd * wv.w + bv.w;
    ((float4*)(outf + (size_t)row * E_))[t] = o;
    if (WRITE_BF16) {
        ushort4 ob;
        ob.x = f2bf(o.x); ob.y = f2bf(o.y); ob.z = f2bf(o.z); ob.w = f2bf(o.w);
        ((ushort4*)(outb + (size_t)row * E_))[t] = ob;
    }
}

extern "C" void kernel_launch(void* const* d_in, const int* in_sizes, int n_in,
                              void* d_out, int out_size, void* d_ws, size_t ws_size,
                              hipStream_t stream) {
    const float* x        = (const float*)d_in[0];
    const int*   am       = (const int*)d_in[1];
    const int*   tt       = (const int*)d_in[2];
    const float* in_w     = (const float*)d_in[3];
    const float* in_b     = (const float*)d_in[4];
    const float* out_w    = (const float*)d_in[5];
    const float* out_b    = (const float*)d_in[6];
    const float* ln_w     = (const float*)d_in[7];
    const float* ln_b     = (const float*)d_in[8];
    const float* w_in     = (const float*)d_in[9];
    const float* b_in     = (const float*)d_in[10];
    const float* w_out    = (const float*)d_in[11];
    const float* b_out    = (const float*)d_in[12];
    float* out = (float*)d_out;

    const size_t MB = 1024 * 1024;
    char* ws = (char*)d_ws;
    unsigned short* xb    = (unsigned short*)(ws + 0);        // 16 MB (reused as hb)
    unsigned short* hb    = xb;
    unsigned short* wqkvT = (unsigned short*)(ws + 16 * MB);  // 6 MB
    unsigned short* woutT = (unsigned short*)(ws + 22 * MB);  // 2 MB
    unsigned short* winT  = (unsigned short*)(ws + 24 * MB);  // 8 MB
    unsigned short* wo2T  = (unsigned short*)(ws + 32 * MB);  // 8 MB
    unsigned short* qkvb  = (unsigned short*)(ws + 40 * MB);  // 48 MB
    unsigned short* vT    = (unsigned short*)(ws + 88 * MB);  // 16 MB
    unsigned short* ctx   = (unsigned short*)(ws + 104 * MB); // 16 MB
    float*          res1  = (float*)(ws + 120 * MB);          // 32 MB (reused for res2)
    float*          hbuf  = (float*)(ws + 152 * MB);          // 32 MB
    unsigned short* ffmid = (unsigned short*)(ws + 184 * MB); // 64 MB  -> total 248 MB

    // 1. cast x -> bf16
    cast_f32_bf16<<<dim3(M_ * E_ / 1024), 256, 0, stream>>>(x, xb);
    // 2. transpose-cast weights
    transpose_cast<<<dim3(3 * E_ / 32, E_ / 32), 256, 0, stream>>>(in_w, wqkvT, E_, 3 * E_);
    transpose_cast<<<dim3(E_ / 32, E_ / 32), 256, 0, stream>>>(out_w, woutT, E_, E_);
    transpose_cast<<<dim3(F_ / 32, E_ / 32), 256, 0, stream>>>(w_in, winT, E_, F_);
    transpose_cast<<<dim3(E_ / 32, F_ / 32), 256, 0, stream>>>(w_out, wo2T, F_, E_);
    // 3. qkv = x @ in_proj_w + in_proj_b  (q scaled by 1/8)
    gemm_bt<0><<<dim3(3 * E_ / BN, M_ / BM), 256, 0, stream>>>(xb, wqkvT, in_b, nullptr,
                                                               qkvb, nullptr, M_, 3 * E_, E_);
    // 4. vT
    transpose_v<<<dim3(S_ / 64, B_ * H_), 256, 0, stream>>>(qkvb, vT);
    // 5. attention -> ctx
    attn_kernel<<<dim3(S_ / 16, B_ * H_), 256, 0, stream>>>(qkvb, vT, am, tt, ctx);
    // 6. attn_out + x  (fp32)
    gemm_bt<2><<<dim3(E_ / BN, M_ / BM), 256, 0, stream>>>(ctx, woutT, out_b, x,
                                                           nullptr, res1, M_, E_, E_);
    // 7. LN1 -> hbuf (f32) + hb (bf16)
    ln_kernel<1><<<dim3(M_), 256, 0, stream>>>(res1, ln_w, ln_b, hbuf, hb);
    // 8. ffmid = gelu(h @ w_in + b_in)
    gemm_bt<1><<<dim3(F_ / BN, M_ / BM), 256, 0, stream>>>(hb, winT, b_in, nullptr,
                                                           ffmid, nullptr, M_, F_, E_);
    // 9. ff + h (fp32)
    gemm_bt<2><<<dim3(E_ / BN, M_ / BM), 256, 0, stream>>>(ffmid, wo2T, b_out, hbuf,
                                                           nullptr, res1, M_, E_, F_);
    // 10. LN2 -> out
    ln_kernel<0><<<dim3(M_), 256, 0, stream>>>(res1, ln_w, ln_b, out, nullptr);
}

// Round 2
// 761.741 us; speedup vs baseline: 2.6325x; 2.6325x over previous
//
#include <hip/hip_runtime.h>
#include <hip/hip_bf16.h>
#include <math.h>

#define B_ 8
#define S_ 1024
#define E_ 1024
#define H_ 16
#define HD_ 64
#define F_ 4096
#define M_ (B_ * S_)   // 8192

typedef float f32x4 __attribute__((ext_vector_type(4)));
typedef short short8 __attribute__((ext_vector_type(8)));

__device__ inline unsigned short f2bf(float x) {
    union { float f; unsigned int u; } v; v.f = x;
    unsigned int r = (v.u + 0x7fffu + ((v.u >> 16) & 1u)) >> 16;
    return (unsigned short)r;
}
__device__ inline float bf2f(unsigned short u) {
    union { unsigned int u; float f; } v; v.u = ((unsigned int)u) << 16;
    return v.f;
}

// inline erf, Abramowitz-Stegun 7.1.26, |err| < 1.5e-7 — NO libcall (erff() is a
// real ABI call on this toolchain: it spilled the MFMA accumulators around 64
// calls/thread in the epilogue -> 6.8 GB of scratch traffic, 1347us dispatch)
__device__ inline float erf_inline(float x) {
    float ax = __builtin_fabsf(x);
    float t = __builtin_amdgcn_rcpf(1.0f + 0.3275911f * ax);
    float y = t * (0.254829592f + t * (-0.284496736f + t * (1.421413741f +
              t * (-1.453152027f + t * 1.061405429f))));
    float e = __expf(-ax * ax);
    float r = 1.0f - y * e;
    union { float f; unsigned int u; } s, o;
    s.f = x; o.f = r;
    o.u = (o.u & 0x7fffffffu) | (s.u & 0x80000000u);
    return o.f;
}

#define AS1 __attribute__((address_space(1)))
#define AS3 __attribute__((address_space(3)))
__device__ inline void gload_lds16(const void* g, void* l) {
    __builtin_amdgcn_global_load_lds((const AS1 unsigned int*)(g),
                                     (AS3 unsigned int*)(l), 16, 0, 0);
}

// ---------------- cast x fp32 -> bf16 ----------------
__global__ __launch_bounds__(256) void cast_f32_bf16(const float* __restrict__ in,
                                                     unsigned short* __restrict__ out) {
    int i = (blockIdx.x * 256 + threadIdx.x) * 4;
    float4 v = *(const float4*)(in + i);
    ushort4 o;
    o.x = f2bf(v.x); o.y = f2bf(v.y); o.z = f2bf(v.z); o.w = f2bf(v.w);
    *(ushort4*)(out + i) = o;
}

// ---------------- transpose+cast weight: in[K,N] f32 -> out[N,K] bf16 ----------------
__global__ __launch_bounds__(256) void transpose_cast(const float* __restrict__ in,
                                                      unsigned short* __restrict__ out,
                                                      int K, int N) {
    __shared__ float tile[32][33];
    int n0 = blockIdx.x * 32, k0 = blockIdx.y * 32;
    int tc = threadIdx.x & 31, tr = threadIdx.x >> 5;  // tr 0..7
    for (int i = 0; i < 4; ++i) {
        int k = k0 + tr + i * 8;
        tile[tr + i * 8][tc] = in[(size_t)k * N + n0 + tc];
    }
    __syncthreads();
    for (int i = 0; i < 4; ++i) {
        int n = n0 + tr + i * 8;
        out[(size_t)n * K + k0 + tc] = f2bf(tile[tc][tr + i * 8]);
    }
}

// ---------------- GEMM: C[M,N] = A[M,K](bf16) @ Bt[N,K]^T(bf16) + bias, epilogues ----------------
// EPI 0: qkv  -> bias, scale cols<1024 by 1/8, store bf16
// EPI 1: gelu -> bias, exact gelu (inline erf), store bf16
// EPI 2: res  -> bias + res[row*N+col], store fp32
#define BM 128
#define BN 128
#define BK 32
template <int EPI>
__global__ __launch_bounds__(256) void gemm_bt(const unsigned short* __restrict__ A,
                                               const unsigned short* __restrict__ Bt,
                                               const float* __restrict__ bias,
                                               const float* __restrict__ res,
                                               unsigned short* __restrict__ Cb,
                                               float* __restrict__ Cf,
                                               int M, int N, int K) {
    __shared__ unsigned short lA[BM * BK];
    __shared__ unsigned short lB[BN * BK];
    int row0 = blockIdx.y * BM, col0 = blockIdx.x * BN;
    int t = threadIdx.x;
    int lane = t & 63, w = t >> 6;
    int wr = w >> 1, wc = w & 1;
    int qa = lane >> 4, ml = lane & 15;

    f32x4 acc[4][4] = {};
    const unsigned short* Aptr = A + (size_t)row0 * K;
    const unsigned short* Bptr = Bt + (size_t)col0 * K;

    for (int k0 = 0; k0 < K; k0 += BK) {
        __syncthreads();
        for (int i = 0; i < 2; ++i) {
            int c = t + i * 256;
            int r = c >> 2, kc = c & 3;
            gload_lds16(Aptr + (size_t)r * K + k0 + kc * 8, lA + c * 8);
            gload_lds16(Bptr + (size_t)r * K + k0 + kc * 8, lB + c * 8);
        }
        __syncthreads();
        short8 af[4], bfr[4];
        for (int i = 0; i < 4; ++i)
            af[i] = *(const short8*)&lA[(wr * 64 + i * 16 + ml) * BK + qa * 8];
        for (int j = 0; j < 4; ++j)
            bfr[j] = *(const short8*)&lB[(wc * 64 + j * 16 + ml) * BK + qa * 8];
        for (int i = 0; i < 4; ++i)
            for (int j = 0; j < 4; ++j)
                acc[i][j] = __builtin_amdgcn_mfma_f32_16x16x32_bf16(af[i], bfr[j], acc[i][j], 0, 0, 0);
    }

    for (int i = 0; i < 4; ++i) {
        for (int j = 0; j < 4; ++j) {
            int col = col0 + wc * 64 + j * 16 + ml;
            float bv = bias[col];
            for (int r = 0; r < 4; ++r) {
                int row = row0 + wr * 64 + i * 16 + qa * 4 + r;
                float cv = acc[i][j][r] + bv;
                if (EPI == 0) {
                    if (col < 1024) cv *= 0.125f;
                    Cb[(size_t)row * N + col] = f2bf(cv);
                } else if (EPI == 1) {
                    cv = 0.5f * cv * (1.0f + erf_inline(cv * 0.70710678118654752f));
                    Cb[(size_t)row * N + col] = f2bf(cv);
                } else {
                    cv += res[(size_t)row * N + col];
                    Cf[(size_t)row * N + col] = cv;
                }
            }
        }
    }
}

// ---------------- transpose v slice of qkv -> vT[b,h,d,s] ----------------
__global__ __launch_bounds__(256) void transpose_v(const unsigned short* __restrict__ qkv,
                                                   unsigned short* __restrict__ vT) {
    __shared__ unsigned short tile[64][72];
    int s0 = blockIdx.x * 64;
    int pair = blockIdx.y;
    int b = pair >> 4, h = pair & 15;
    int t = threadIdx.x;
    int r = t >> 2, c0 = (t & 3) * 16;
    const unsigned short* src = qkv + (size_t)(b * S_ + s0 + r) * 3072 + 2048 + h * 64 + c0;
    *(short8*)&tile[r][c0] = *(const short8*)src;
    *(short8*)&tile[r][c0 + 8] = *(const short8*)(src + 8);
    __syncthreads();
    int d = t >> 2, sc0 = (t & 3) * 16;
    unsigned short tmp[16];
    for (int i = 0; i < 16; ++i) tmp[i] = tile[sc0 + i][d];
    unsigned short* dst = vT + ((size_t)pair * 64 + d) * S_ + s0 + sc0;
    *(short8*)dst = *(const short8*)&tmp[0];
    *(short8*)(dst + 8) = *(const short8*)&tmp[8];
}

// ---------------- fused attention: scores -> softmax -> ctx, per (b,h,16 q rows) ----------------
__global__ __launch_bounds__(256) void attn_kernel(const unsigned short* __restrict__ qkv,
                                                   const unsigned short* __restrict__ vT,
                                                   const int* __restrict__ am,
                                                   const int* __restrict__ tt,
                                                   unsigned short* __restrict__ ctx) {
    __shared__ unsigned short sc[16 * 1032];  // padded row stride 1032
    __shared__ unsigned short qtile[16 * 64];
    __shared__ float lsum[16];
    int qb = blockIdx.x;
    int pair = blockIdx.y;
    int b = pair >> 4, h = pair & 15;
    int t = threadIdx.x, w = t >> 6, lane = t & 63;
    int qa = lane >> 4, ml = lane & 15;
    int q0 = qb * 16;

    {   // load q tile [16][64]
        int r = t >> 4, c4 = (t & 15) * 4;
        const unsigned short* src = qkv + (size_t)(b * S_ + q0 + r) * 3072 + h * 64 + c4;
        *(uint2*)&qtile[r * 64 + c4] = *(const uint2*)src;
    }
    __syncthreads();

    short8 aq0 = *(const short8*)&qtile[ml * 64 + qa * 8];
    short8 aq1 = *(const short8*)&qtile[ml * 64 + 32 + qa * 8];
    int amq[4];
    for (int r = 0; r < 4; ++r) amq[r] = am[b * S_ + q0 + qa * 4 + r];

    // score phase: wave w handles key tiles w, w+4, ...
    for (int tile = w; tile < 64; tile += 4) {
        int kk = tile * 16 + ml;
        const unsigned short* kp = qkv + (size_t)(b * S_ + kk) * 3072 + 1024 + h * 64 + qa * 8;
        short8 b0 = *(const short8*)kp;
        short8 b1 = *(const short8*)(kp + 32);
        f32x4 a = {};
        a = __builtin_amdgcn_mfma_f32_16x16x32_bf16(aq0, b0, a, 0, 0, 0);
        a = __builtin_amdgcn_mfma_f32_16x16x32_bf16(aq1, b1, a, 0, 0, 0);
        int amk = am[b * S_ + kk];
        int ttk = tt[b * S_ + kk];
        bool neg = (ttk == 1) || (amk == 0) || (kk == 0);
        for (int r = 0; r < 4; ++r) {
            float s = a[r] + ((amq[r] != 0 && amk != 0) ? 1.0f : 0.0f);
            if (neg) s = -1e30f;
            sc[(qa * 4 + r) * 1032 + tile * 16 + ml] = f2bf(s);
        }
    }
    __syncthreads();

    // softmax: 16 threads per row (contiguous within one wave)
    {
        int r = t >> 4, j = t & 15;
        float mx = -3e38f;
        for (int i = 0; i < 64; ++i) mx = fmaxf(mx, bf2f(sc[r * 1032 + j + 16 * i]));
        for (int o = 8; o >= 1; o >>= 1) mx = fmaxf(mx, __shfl_xor(mx, o, 16));
        float sum = 0.f;
        for (int i = 0; i < 64; ++i) {
            int idx = r * 1032 + j + 16 * i;
            float p = __expf(bf2f(sc[idx]) - mx);
            sum += p;
            sc[idx] = f2bf(p);
        }
        for (int o = 8; o >= 1; o >>= 1) sum += __shfl_xor(sum, o, 16);
        if (j == 0) lsum[r] = sum;
    }
    __syncthreads();

    // ctx phase: wave w -> d-tile w (cols w*16 .. w*16+15)
    f32x4 a = {};
    const unsigned short* vtp = vT + ((size_t)pair * 64 + w * 16 + ml) * S_;
    for (int k0 = 0; k0 < S_; k0 += 32) {
        short8 ap = *(const short8*)&sc[ml * 1032 + k0 + qa * 8];
        short8 bp = *(const short8*)(vtp + k0 + qa * 8);
        a = __builtin_amdgcn_mfma_f32_16x16x32_bf16(ap, bp, a, 0, 0, 0);
    }
    for (int r = 0; r < 4; ++r) {
        int row = qa * 4 + r;
        float inv = 1.0f / lsum[row];
        ctx[(size_t)(b * S_ + q0 + row) * E_ + h * 64 + w * 16 + ml] = f2bf(a[r] * inv);
    }
}

// ---------------- row LayerNorm over E=1024 ----------------
template <int WRITE_BF16>
__global__ __launch_bounds__(256) void ln_kernel(const float* __restrict__ in,
                                                 const float* __restrict__ lw,
                                                 const float* __restrict__ lb,
                                                 float* __restrict__ outf,
                                                 unsigned short* __restrict__ outb) {
    int row = blockIdx.x;
    int t = threadIdx.x;
    const float* x = in + (size_t)row * E_;
    float4 v = ((const float4*)x)[t];
    float s = v.x + v.y + v.z + v.w;
    float sq = v.x * v.x + v.y * v.y + v.z * v.z + v.w * v.w;
    for (int o = 32; o >= 1; o >>= 1) {
        s += __shfl_xor(s, o, 64);
        sq += __shfl_xor(sq, o, 64);
    }
    __shared__ float red[8];
    if ((t & 63) == 0) { red[t >> 6] = s; red[4 + (t >> 6)] = sq; }
    __syncthreads();
    s = red[0] + red[1] + red[2] + red[3];
    sq = red[4] + red[5] + red[6] + red[7];
    float mu = s * (1.0f / E_);
    float var = sq * (1.0f / E_) - mu * mu;
    float rstd = rsqrtf(fmaxf(var, 0.0f) + 1e-12f);
    float4 wv = ((const float4*)lw)[t];
    float4 bv = ((const float4*)lb)[t];
    float4 o;
    o.x = (v.x - mu) * rstd * wv.x + bv.x;
    o.y = (v.y - mu) * rstd * wv.y + bv.y;
    o.z = (v.z - mu) * rstd * wv.z + bv.z;
    o.w = (v.w - mu) * rstd * wv.w + bv.w;
    ((float4*)(outf + (size_t)row * E_))[t] = o;
    if (WRITE_BF16) {
        ushort4 ob;
        ob.x = f2bf(o.x); ob.y = f2bf(o.y); ob.z = f2bf(o.z); ob.w = f2bf(o.w);
        ((ushort4*)(outb + (size_t)row * E_))[t] = ob;
    }
}

extern "C" void kernel_launch(void* const* d_in, const int* in_sizes, int n_in,
                              void* d_out, int out_size, void* d_ws, size_t ws_size,
                              hipStream_t stream) {
    const float* x        = (const float*)d_in[0];
    const int*   am       = (const int*)d_in[1];
    const int*   tt       = (const int*)d_in[2];
    const float* in_w     = (const float*)d_in[3];
    const float* in_b     = (const float*)d_in[4];
    const float* out_w    = (const float*)d_in[5];
    const float* out_b    = (const float*)d_in[6];
    const float* ln_w     = (const float*)d_in[7];
    const float* ln_b     = (const float*)d_in[8];
    const float* w_in     = (const float*)d_in[9];
    const float* b_in     = (const float*)d_in[10];
    const float* w_out    = (const float*)d_in[11];
    const float* b_out    = (const float*)d_in[12];
    float* out = (float*)d_out;

    const size_t MB = 1024 * 1024;
    char* ws = (char*)d_ws;
    unsigned short* xb    = (unsigned short*)(ws + 0);        // 16 MB (reused as hb)
    unsigned short* hb    = xb;
    unsigned short* wqkvT = (unsigned short*)(ws + 16 * MB);  // 6 MB
    unsigned short* woutT = (unsigned short*)(ws + 22 * MB);  // 2 MB
    unsigned short* winT  = (unsigned short*)(ws + 24 * MB);  // 8 MB
    unsigned short* wo2T  = (unsigned short*)(ws + 32 * MB);  // 8 MB
    unsigned short* qkvb  = (unsigned short*)(ws + 40 * MB);  // 48 MB
    unsigned short* vT    = (unsigned short*)(ws + 88 * MB);  // 16 MB
    unsigned short* ctx   = (unsigned short*)(ws + 104 * MB); // 16 MB
    float*          res1  = (float*)(ws + 120 * MB);          // 32 MB (reused for res2)
    float*          hbuf  = (float*)(ws + 152 * MB);          // 32 MB
    unsigned short* ffmid = (unsigned short*)(ws + 184 * MB); // 64 MB  -> total 248 MB

    // 1. cast x -> bf16
    cast_f32_bf16<<<dim3(M_ * E_ / 1024), 256, 0, stream>>>(x, xb);
    // 2. transpose-cast weights
    transpose_cast<<<dim3(3 * E_ / 32, E_ / 32), 256, 0, stream>>>(in_w, wqkvT, E_, 3 * E_);
    transpose_cast<<<dim3(E_ / 32, E_ / 32), 256, 0, stream>>>(out_w, woutT, E_, E_);
    transpose_cast<<<dim3(F_ / 32, E_ / 32), 256, 0, stream>>>(w_in, winT, E_, F_);
    transpose_cast<<<dim3(E_ / 32, F_ / 32), 256, 0, stream>>>(w_out, wo2T, F_, E_);
    // 3. qkv = x @ in_proj_w + in_proj_b  (q scaled by 1/8)
    gemm_bt<0><<<dim3(3 * E_ / BN, M_ / BM), 256, 0, stream>>>(xb, wqkvT, in_b, nullptr,
                                                               qkvb, nullptr, M_, 3 * E_, E_);
    // 4. vT
    transpose_v<<<dim3(S_ / 64, B_ * H_), 256, 0, stream>>>(qkvb, vT);
    // 5. attention -> ctx
    attn_kernel<<<dim3(S_ / 16, B_ * H_), 256, 0, stream>>>(qkvb, vT, am, tt, ctx);
    // 6. attn_out + x  (fp32)
    gemm_bt<2><<<dim3(E_ / BN, M_ / BM), 256, 0, stream>>>(ctx, woutT, out_b, x,
                                                           nullptr, res1, M_, E_, E_);
    // 7. LN1 -> hbuf (f32) + hb (bf16)
    ln_kernel<1><<<dim3(M_), 256, 0, stream>>>(res1, ln_w, ln_b, hbuf, hb);
    // 8. ffmid = gelu(h @ w_in + b_in)
    gemm_bt<1><<<dim3(F_ / BN, M_ / BM), 256, 0, stream>>>(hb, winT, b_in, nullptr,
                                                           ffmid, nullptr, M_, F_, E_);
    // 9. ff + h (fp32)
    gemm_bt<2><<<dim3(E_ / BN, M_ / BM), 256, 0, stream>>>(ffmid, wo2T, b_out, hbuf,
                                                           nullptr, res1, M_, E_, F_);
    // 10. LN2 -> out
    ln_kernel<0><<<dim3(M_), 256, 0, stream>>>(res1, ln_w, ln_b, out, nullptr);
}

// Round 3
// 750.872 us; speedup vs baseline: 2.6706x; 1.0145x over previous
//
#include <hip/hip_runtime.h>
#include <hip/hip_bf16.h>
#include <math.h>

#define B_ 8
#define S_ 1024
#define E_ 1024
#define H_ 16
#define HD_ 64
#define F_ 4096
#define M_ (B_ * S_)   // 8192

typedef float f32x4 __attribute__((ext_vector_type(4)));
typedef short short8 __attribute__((ext_vector_type(8)));

__device__ inline unsigned short f2bf(float x) {
    union { float f; unsigned int u; } v; v.f = x;
    unsigned int r = (v.u + 0x7fffu + ((v.u >> 16) & 1u)) >> 16;
    return (unsigned short)r;
}
__device__ inline float bf2f(unsigned short u) {
    union { unsigned int u; float f; } v; v.u = ((unsigned int)u) << 16;
    return v.f;
}

// inline erf, Abramowitz-Stegun 7.1.26, |err| < 1.5e-7 — NO libcall (erff() is a
// real ABI call on this toolchain: it spilled the MFMA accumulators around 64
// calls/thread in the epilogue -> 6.8 GB of scratch traffic, 1347us dispatch)
__device__ inline float erf_inline(float x) {
    float ax = __builtin_fabsf(x);
    float t = __builtin_amdgcn_rcpf(1.0f + 0.3275911f * ax);
    float y = t * (0.254829592f + t * (-0.284496736f + t * (1.421413741f +
              t * (-1.453152027f + t * 1.061405429f))));
    float e = __expf(-ax * ax);
    float r = 1.0f - y * e;
    union { float f; unsigned int u; } s, o;
    s.f = x; o.f = r;
    o.u = (o.u & 0x7fffffffu) | (s.u & 0x80000000u);
    return o.f;
}

#define AS1 __attribute__((address_space(1)))
#define AS3 __attribute__((address_space(3)))
__device__ inline void gload_lds16(const void* g, void* l) {
    __builtin_amdgcn_global_load_lds((const AS1 unsigned int*)(g),
                                     (AS3 unsigned int*)(l), 16, 0, 0);
}

// ---------------- cast x fp32 -> bf16 ----------------
__global__ __launch_bounds__(256) void cast_f32_bf16(const float* __restrict__ in,
                                                     unsigned short* __restrict__ out) {
    int i = (blockIdx.x * 256 + threadIdx.x) * 4;
    float4 v = *(const float4*)(in + i);
    ushort4 o;
    o.x = f2bf(v.x); o.y = f2bf(v.y); o.z = f2bf(v.z); o.w = f2bf(v.w);
    *(ushort4*)(out + i) = o;
}

// ---------------- transpose+cast weight: in[K,N] f32 -> out[N,K] bf16 ----------------
__global__ __launch_bounds__(256) void transpose_cast(const float* __restrict__ in,
                                                      unsigned short* __restrict__ out,
                                                      int K, int N) {
    __shared__ float tile[32][33];
    int n0 = blockIdx.x * 32, k0 = blockIdx.y * 32;
    int tc = threadIdx.x & 31, tr = threadIdx.x >> 5;  // tr 0..7
    for (int i = 0; i < 4; ++i) {
        int k = k0 + tr + i * 8;
        tile[tr + i * 8][tc] = in[(size_t)k * N + n0 + tc];
    }
    __syncthreads();
    for (int i = 0; i < 4; ++i) {
        int n = n0 + tr + i * 8;
        out[(size_t)n * K + k0 + tc] = f2bf(tile[tc][tr + i * 8]);
    }
}

// ---------------- GEMM: C[M,N] = A[M,K](bf16) @ Bt[N,K]^T(bf16) + bias, epilogues ----------------
// EPI 0: qkv  -> bias, scale cols<1024 by 1/8, store bf16
// EPI 1: gelu -> bias, exact gelu (inline erf), store bf16
// EPI 2: res  -> bias + res[row*N+col], store fp32
#define BM 128
#define BN 128
#define BK 32
template <int EPI>
__global__ __launch_bounds__(256) void gemm_bt(const unsigned short* __restrict__ A,
                                               const unsigned short* __restrict__ Bt,
                                               const float* __restrict__ bias,
                                               const float* __restrict__ res,
                                               unsigned short* __restrict__ Cb,
                                               float* __restrict__ Cf,
                                               int M, int N, int K) {
    __shared__ unsigned short lA[BM * BK];
    __shared__ unsigned short lB[BN * BK];
    int row0 = blockIdx.y * BM, col0 = blockIdx.x * BN;
    int t = threadIdx.x;
    int lane = t & 63, w = t >> 6;
    int wr = w >> 1, wc = w & 1;
    int qa = lane >> 4, ml = lane & 15;

    f32x4 acc[4][4] = {};
    const unsigned short* Aptr = A + (size_t)row0 * K;
    const unsigned short* Bptr = Bt + (size_t)col0 * K;

    for (int k0 = 0; k0 < K; k0 += BK) {
        __syncthreads();
        for (int i = 0; i < 2; ++i) {
            int c = t + i * 256;
            int r = c >> 2, kc = c & 3;
            gload_lds16(Aptr + (size_t)r * K + k0 + kc * 8, lA + c * 8);
            gload_lds16(Bptr + (size_t)r * K + k0 + kc * 8, lB + c * 8);
        }
        __syncthreads();
        short8 af[4], bfr[4];
        for (int i = 0; i < 4; ++i)
            af[i] = *(const short8*)&lA[(wr * 64 + i * 16 + ml) * BK + qa * 8];
        for (int j = 0; j < 4; ++j)
            bfr[j] = *(const short8*)&lB[(wc * 64 + j * 16 + ml) * BK + qa * 8];
        for (int i = 0; i < 4; ++i)
            for (int j = 0; j < 4; ++j)
                acc[i][j] = __builtin_amdgcn_mfma_f32_16x16x32_bf16(af[i], bfr[j], acc[i][j], 0, 0, 0);
    }

    for (int i = 0; i < 4; ++i) {
        for (int j = 0; j < 4; ++j) {
            int col = col0 + wc * 64 + j * 16 + ml;
            float bv = bias[col];
            for (int r = 0; r < 4; ++r) {
                int row = row0 + wr * 64 + i * 16 + qa * 4 + r;
                float cv = acc[i][j][r] + bv;
                if (EPI == 0) {
                    if (col < 1024) cv *= 0.125f;
                    Cb[(size_t)row * N + col] = f2bf(cv);
                } else if (EPI == 1) {
                    cv = 0.5f * cv * (1.0f + erf_inline(cv * 0.70710678118654752f));
                    Cb[(size_t)row * N + col] = f2bf(cv);
                } else {
                    cv += res[(size_t)row * N + col];
                    Cf[(size_t)row * N + col] = cv;
                }
            }
        }
    }
}

// ---------------- transpose v slice of qkv -> vT[b,h,d,s] ----------------
__global__ __launch_bounds__(256) void transpose_v(const unsigned short* __restrict__ qkv,
                                                   unsigned short* __restrict__ vT) {
    __shared__ unsigned short tile[64][72];
    int s0 = blockIdx.x * 64;
    int pair = blockIdx.y;
    int b = pair >> 4, h = pair & 15;
    int t = threadIdx.x;
    int r = t >> 2, c0 = (t & 3) * 16;
    const unsigned short* src = qkv + (size_t)(b * S_ + s0 + r) * 3072 + 2048 + h * 64 + c0;
    *(short8*)&tile[r][c0] = *(const short8*)src;
    *(short8*)&tile[r][c0 + 8] = *(const short8*)(src + 8);
    __syncthreads();
    int d = t >> 2, sc0 = (t & 3) * 16;
    unsigned short tmp[16];
    for (int i = 0; i < 16; ++i) tmp[i] = tile[sc0 + i][d];
    unsigned short* dst = vT + ((size_t)pair * 64 + d) * S_ + s0 + sc0;
    *(short8*)dst = *(const short8*)&tmp[0];
    *(short8*)(dst + 8) = *(const short8*)&tmp[8];
}

// ---------------- fused attention: scores -> softmax -> ctx, per (b,h,16 q rows) ----------------
// v2: row-max folded into score phase (register + 16-lane shuffle, no LDS max pass);
//     exp+sum pass uses contiguous ds_read_b128/ds_write_b128 (row = t&15, chunk = t>>4,
//     bank = 4*row -> 2-way aliasing only). Was: 192 scalar LDS ops/thread, 1.76e7 conflicts.
__global__ __launch_bounds__(256) void attn_kernel(const unsigned short* __restrict__ qkv,
                                                   const unsigned short* __restrict__ vT,
                                                   const int* __restrict__ am,
                                                   const int* __restrict__ tt,
                                                   unsigned short* __restrict__ ctx) {
    __shared__ unsigned short sc[16 * 1032];  // padded row stride 1032 shorts (16B-aligned rows)
    __shared__ unsigned short qtile[16 * 64];
    __shared__ float wmax[4 * 16];            // per-wave row maxima
    __shared__ float pr[16 * 16];             // partial sums [row][chunk]
    __shared__ float lsum[16];
    int qb = blockIdx.x;
    int pair = blockIdx.y;
    int b = pair >> 4, h = pair & 15;
    int t = threadIdx.x, w = t >> 6, lane = t & 63;
    int qa = lane >> 4, ml = lane & 15;
    int q0 = qb * 16;

    {   // load q tile [16][64]
        int r = t >> 4, c4 = (t & 15) * 4;
        const unsigned short* src = qkv + (size_t)(b * S_ + q0 + r) * 3072 + h * 64 + c4;
        *(uint2*)&qtile[r * 64 + c4] = *(const uint2*)src;
    }
    __syncthreads();

    short8 aq0 = *(const short8*)&qtile[ml * 64 + qa * 8];
    short8 aq1 = *(const short8*)&qtile[ml * 64 + 32 + qa * 8];
    int amq[4];
    for (int r = 0; r < 4; ++r) amq[r] = am[b * S_ + q0 + qa * 4 + r];

    // score phase: wave w handles key tiles w, w+4, ...; track row max in registers
    float mrow[4] = {-3e38f, -3e38f, -3e38f, -3e38f};
    for (int tile = w; tile < 64; tile += 4) {
        int kk = tile * 16 + ml;
        const unsigned short* kp = qkv + (size_t)(b * S_ + kk) * 3072 + 1024 + h * 64 + qa * 8;
        short8 b0 = *(const short8*)kp;
        short8 b1 = *(const short8*)(kp + 32);
        f32x4 a = {};
        a = __builtin_amdgcn_mfma_f32_16x16x32_bf16(aq0, b0, a, 0, 0, 0);
        a = __builtin_amdgcn_mfma_f32_16x16x32_bf16(aq1, b1, a, 0, 0, 0);
        int amk = am[b * S_ + kk];
        int ttk = tt[b * S_ + kk];
        bool neg = (ttk == 1) || (amk == 0) || (kk == 0);
        for (int r = 0; r < 4; ++r) {
            float s = a[r] + ((amq[r] != 0 && amk != 0) ? 1.0f : 0.0f);
            if (neg) s = -1e30f;
            unsigned short sb = f2bf(s);
            sc[(qa * 4 + r) * 1032 + tile * 16 + ml] = sb;
            mrow[r] = fmaxf(mrow[r], bf2f(sb));   // max of the ROUNDED value
        }
    }
    // reduce row max over the 16 ml-lanes (same qa group => same rows)
    for (int o = 8; o >= 1; o >>= 1)
        for (int r = 0; r < 4; ++r)
            mrow[r] = fmaxf(mrow[r], __shfl_xor(mrow[r], o, 16));
    if (ml == 0)
        for (int r = 0; r < 4; ++r)
            wmax[w * 16 + qa * 4 + r] = mrow[r];
    __syncthreads();

    // exp + partial-sum pass: thread t -> row = t&15, contiguous 64-col chunk = t>>4
    {
        int r = t & 15, ch = t >> 4;
        float m = fmaxf(fmaxf(wmax[r], wmax[16 + r]), fmaxf(wmax[32 + r], wmax[48 + r]));
        float sum = 0.f;
        unsigned short* base = &sc[r * 1032 + ch * 64];
        for (int i = 0; i < 8; ++i) {
            short8 v = *(const short8*)(base + i * 8);
            short8 o;
            for (int j = 0; j < 8; ++j) {
                float p = __expf(bf2f((unsigned short)v[j]) - m);
                sum += p;
                o[j] = (short)f2bf(p);
            }
            *(short8*)(base + i * 8) = o;
        }
        pr[r * 16 + ch] = sum;
    }
    __syncthreads();
    {   // per-row total: 16 contiguous threads per row, shuffle-reduce
        int rr = t >> 4, j = t & 15;
        float s = pr[rr * 16 + j];
        for (int o = 8; o >= 1; o >>= 1) s += __shfl_xor(s, o, 16);
        if (j == 0) lsum[rr] = s;
    }
    __syncthreads();

    // ctx phase: wave w -> d-tile w (cols w*16 .. w*16+15)
    f32x4 a = {};
    const unsigned short* vtp = vT + ((size_t)pair * 64 + w * 16 + ml) * S_;
    for (int k0 = 0; k0 < S_; k0 += 32) {
        short8 ap = *(const short8*)&sc[ml * 1032 + k0 + qa * 8];
        short8 bp = *(const short8*)(vtp + k0 + qa * 8);
        a = __builtin_amdgcn_mfma_f32_16x16x32_bf16(ap, bp, a, 0, 0, 0);
    }
    for (int r = 0; r < 4; ++r) {
        int row = qa * 4 + r;
        float inv = 1.0f / lsum[row];
        ctx[(size_t)(b * S_ + q0 + row) * E_ + h * 64 + w * 16 + ml] = f2bf(a[r] * inv);
    }
}

// ---------------- row LayerNorm over E=1024 ----------------
template <int WRITE_BF16>
__global__ __launch_bounds__(256) void ln_kernel(const float* __restrict__ in,
                                                 const float* __restrict__ lw,
                                                 const float* __restrict__ lb,
                                                 float* __restrict__ outf,
                                                 unsigned short* __restrict__ outb) {
    int row = blockIdx.x;
    int t = threadIdx.x;
    const float* x = in + (size_t)row * E_;
    float4 v = ((const float4*)x)[t];
    float s = v.x + v.y + v.z + v.w;
    float sq = v.x * v.x + v.y * v.y + v.z * v.z + v.w * v.w;
    for (int o = 32; o >= 1; o >>= 1) {
        s += __shfl_xor(s, o, 64);
        sq += __shfl_xor(sq, o, 64);
    }
    __shared__ float red[8];
    if ((t & 63) == 0) { red[t >> 6] = s; red[4 + (t >> 6)] = sq; }
    __syncthreads();
    s = red[0] + red[1] + red[2] + red[3];
    sq = red[4] + red[5] + red[6] + red[7];
    float mu = s * (1.0f / E_);
    float var = sq * (1.0f / E_) - mu * mu;
    float rstd = rsqrtf(fmaxf(var, 0.0f) + 1e-12f);
    float4 wv = ((const float4*)lw)[t];
    float4 bv = ((const float4*)lb)[t];
    float4 o;
    o.x = (v.x - mu) * rstd * wv.x + bv.x;
    o.y = (v.y - mu) * rstd * wv.y + bv.y;
    o.z = (v.z - mu) * rstd * wv.z + bv.z;
    o.w = (v.w - mu) * rstd * wv.w + bv.w;
    ((float4*)(outf + (size_t)row * E_))[t] = o;
    if (WRITE_BF16) {
        ushort4 ob;
        ob.x = f2bf(o.x); ob.y = f2bf(o.y); ob.z = f2bf(o.z); ob.w = f2bf(o.w);
        ((ushort4*)(outb + (size_t)row * E_))[t] = ob;
    }
}

extern "C" void kernel_launch(void* const* d_in, const int* in_sizes, int n_in,
                              void* d_out, int out_size, void* d_ws, size_t ws_size,
                              hipStream_t stream) {
    const float* x        = (const float*)d_in[0];
    const int*   am       = (const int*)d_in[1];
    const int*   tt       = (const int*)d_in[2];
    const float* in_w     = (const float*)d_in[3];
    const float* in_b     = (const float*)d_in[4];
    const float* out_w    = (const float*)d_in[5];
    const float* out_b    = (const float*)d_in[6];
    const float* ln_w     = (const float*)d_in[7];
    const float* ln_b     = (const float*)d_in[8];
    const float* w_in     = (const float*)d_in[9];
    const float* b_in     = (const float*)d_in[10];
    const float* w_out    = (const float*)d_in[11];
    const float* b_out    = (const float*)d_in[12];
    float* out = (float*)d_out;

    const size_t MB = 1024 * 1024;
    char* ws = (char*)d_ws;
    unsigned short* xb    = (unsigned short*)(ws + 0);        // 16 MB (reused as hb)
    unsigned short* hb    = xb;
    unsigned short* wqkvT = (unsigned short*)(ws + 16 * MB);  // 6 MB
    unsigned short* woutT = (unsigned short*)(ws + 22 * MB);  // 2 MB
    unsigned short* winT  = (unsigned short*)(ws + 24 * MB);  // 8 MB
    unsigned short* wo2T  = (unsigned short*)(ws + 32 * MB);  // 8 MB
    unsigned short* qkvb  = (unsigned short*)(ws + 40 * MB);  // 48 MB
    unsigned short* vT    = (unsigned short*)(ws + 88 * MB);  // 16 MB
    unsigned short* ctx   = (unsigned short*)(ws + 104 * MB); // 16 MB
    float*          res1  = (float*)(ws + 120 * MB);          // 32 MB (reused for res2)
    float*          hbuf  = (float*)(ws + 152 * MB);          // 32 MB
    unsigned short* ffmid = (unsigned short*)(ws + 184 * MB); // 64 MB  -> total 248 MB

    // 1. cast x -> bf16
    cast_f32_bf16<<<dim3(M_ * E_ / 1024), 256, 0, stream>>>(x, xb);
    // 2. transpose-cast weights
    transpose_cast<<<dim3(3 * E_ / 32, E_ / 32), 256, 0, stream>>>(in_w, wqkvT, E_, 3 * E_);
    transpose_cast<<<dim3(E_ / 32, E_ / 32), 256, 0, stream>>>(out_w, woutT, E_, E_);
    transpose_cast<<<dim3(F_ / 32, E_ / 32), 256, 0, stream>>>(w_in, winT, E_, F_);
    transpose_cast<<<dim3(E_ / 32, F_ / 32), 256, 0, stream>>>(w_out, wo2T, F_, E_);
    // 3. qkv = x @ in_proj_w + in_proj_b  (q scaled by 1/8)
    gemm_bt<0><<<dim3(3 * E_ / BN, M_ / BM), 256, 0, stream>>>(xb, wqkvT, in_b, nullptr,
                                                               qkvb, nullptr, M_, 3 * E_, E_);
    // 4. vT
    transpose_v<<<dim3(S_ / 64, B_ * H_), 256, 0, stream>>>(qkvb, vT);
    // 5. attention -> ctx
    attn_kernel<<<dim3(S_ / 16, B_ * H_), 256, 0, stream>>>(qkvb, vT, am, tt, ctx);
    // 6. attn_out + x  (fp32)
    gemm_bt<2><<<dim3(E_ / BN, M_ / BM), 256, 0, stream>>>(ctx, woutT, out_b, x,
                                                           nullptr, res1, M_, E_, E_);
    // 7. LN1 -> hbuf (f32) + hb (bf16)
    ln_kernel<1><<<dim3(M_), 256, 0, stream>>>(res1, ln_w, ln_b, hbuf, hb);
    // 8. ffmid = gelu(h @ w_in + b_in)
    gemm_bt<1><<<dim3(F_ / BN, M_ / BM), 256, 0, stream>>>(hb, winT, b_in, nullptr,
                                                           ffmid, nullptr, M_, F_, E_);
    // 9. ff + h (fp32)
    gemm_bt<2><<<dim3(E_ / BN, M_ / BM), 256, 0, stream>>>(ffmid, wo2T, b_out, hbuf,
                                                           nullptr, res1, M_, E_, F_);
    // 10. LN2 -> out
    ln_kernel<0><<<dim3(M_), 256, 0, stream>>>(res1, ln_w, ln_b, out, nullptr);
}

// Round 5
// 686.742 us; speedup vs baseline: 2.9200x; 1.0934x over previous
//
#include <hip/hip_runtime.h>
#include <hip/hip_bf16.h>
#include <math.h>

#define B_ 8
#define S_ 1024
#define E_ 1024
#define H_ 16
#define HD_ 64
#define F_ 4096
#define M_ (B_ * S_)   // 8192

typedef float f32x4 __attribute__((ext_vector_type(4)));
typedef short short8 __attribute__((ext_vector_type(8)));

__device__ inline unsigned short f2bf(float x) {
    union { float f; unsigned int u; } v; v.f = x;
    unsigned int r = (v.u + 0x7fffu + ((v.u >> 16) & 1u)) >> 16;
    return (unsigned short)r;
}
__device__ inline float bf2f(unsigned short u) {
    union { unsigned int u; float f; } v; v.u = ((unsigned int)u) << 16;
    return v.f;
}

// inline erf, Abramowitz-Stegun 7.1.26, |err| < 1.5e-7 — NO libcall (erff() is a
// real ABI call on this toolchain: it spilled the MFMA accumulators around 64
// calls/thread in the epilogue -> 6.8 GB of scratch traffic, 1347us dispatch)
__device__ inline float erf_inline(float x) {
    float ax = __builtin_fabsf(x);
    float t = __builtin_amdgcn_rcpf(1.0f + 0.3275911f * ax);
    float y = t * (0.254829592f + t * (-0.284496736f + t * (1.421413741f +
              t * (-1.453152027f + t * 1.061405429f))));
    float e = __expf(-ax * ax);
    float r = 1.0f - y * e;
    union { float f; unsigned int u; } s, o;
    s.f = x; o.f = r;
    o.u = (o.u & 0x7fffffffu) | (s.u & 0x80000000u);
    return o.f;
}

#define AS1 __attribute__((address_space(1)))
#define AS3 __attribute__((address_space(3)))
__device__ inline void gload_lds16(const void* g, void* l) {
    __builtin_amdgcn_global_load_lds((const AS1 unsigned int*)(g),
                                     (AS3 unsigned int*)(l), 16, 0, 0);
}

// ---------------- cast x fp32 -> bf16 ----------------
__global__ __launch_bounds__(256) void cast_f32_bf16(const float* __restrict__ in,
                                                     unsigned short* __restrict__ out) {
    int i = (blockIdx.x * 256 + threadIdx.x) * 4;
    float4 v = *(const float4*)(in + i);
    ushort4 o;
    o.x = f2bf(v.x); o.y = f2bf(v.y); o.z = f2bf(v.z); o.w = f2bf(v.w);
    *(ushort4*)(out + i) = o;
}

// ---------------- mask prep: per (b,s) additive -1e30/0 and q-side 0/1 float ----------------
__global__ __launch_bounds__(256) void mask_prep(const int* __restrict__ am,
                                                 const int* __restrict__ tt,
                                                 float* __restrict__ amqf,
                                                 float* __restrict__ negadd) {
    int i = blockIdx.x * 256 + threadIdx.x;   // i in [0, B*S)
    int s = i & (S_ - 1);
    int a = am[i], t = tt[i];
    amqf[i] = (a != 0) ? 1.0f : 0.0f;
    negadd[i] = ((t == 1) || (a == 0) || (s == 0)) ? -1e30f : 0.0f;
}

// ---------------- transpose+cast weight: in[K,N] f32 -> out[N,K] bf16 ----------------
__global__ __launch_bounds__(256) void transpose_cast(const float* __restrict__ in,
                                                      unsigned short* __restrict__ out,
                                                      int K, int N) {
    __shared__ float tile[32][33];
    int n0 = blockIdx.x * 32, k0 = blockIdx.y * 32;
    int tc = threadIdx.x & 31, tr = threadIdx.x >> 5;  // tr 0..7
    for (int i = 0; i < 4; ++i) {
        int k = k0 + tr + i * 8;
        tile[tr + i * 8][tc] = in[(size_t)k * N + n0 + tc];
    }
    __syncthreads();
    for (int i = 0; i < 4; ++i) {
        int n = n0 + tr + i * 8;
        out[(size_t)n * K + k0 + tc] = f2bf(tile[tc][tr + i * 8]);
    }
}

// ---------------- GEMM: C[M,N] = A[M,K](bf16) @ Bt[N,K]^T(bf16) + bias, epilogues ----------------
// EPI 0: qkv  -> bias, scale cols<1024 by 1/8, store bf16
// EPI 1: gelu -> bias, exact gelu (inline erf), store bf16
// EPI 2: res  -> bias + res[row*N+col], store fp32
#define BM 128
#define BN 128
#define BK 32
template <int EPI>
__global__ __launch_bounds__(256) void gemm_bt(const unsigned short* __restrict__ A,
                                               const unsigned short* __restrict__ Bt,
                                               const float* __restrict__ bias,
                                               const float* __restrict__ res,
                                               unsigned short* __restrict__ Cb,
                                               float* __restrict__ Cf,
                                               int M, int N, int K) {
    __shared__ unsigned short lA[BM * BK];
    __shared__ unsigned short lB[BN * BK];
    int row0 = blockIdx.y * BM, col0 = blockIdx.x * BN;
    int t = threadIdx.x;
    int lane = t & 63, w = t >> 6;
    int wr = w >> 1, wc = w & 1;
    int qa = lane >> 4, ml = lane & 15;

    f32x4 acc[4][4] = {};
    const unsigned short* Aptr = A + (size_t)row0 * K;
    const unsigned short* Bptr = Bt + (size_t)col0 * K;

    for (int k0 = 0; k0 < K; k0 += BK) {
        __syncthreads();
        for (int i = 0; i < 2; ++i) {
            int c = t + i * 256;
            int r = c >> 2, kc = c & 3;
            gload_lds16(Aptr + (size_t)r * K + k0 + kc * 8, lA + c * 8);
            gload_lds16(Bptr + (size_t)r * K + k0 + kc * 8, lB + c * 8);
        }
        __syncthreads();
        short8 af[4], bfr[4];
        for (int i = 0; i < 4; ++i)
            af[i] = *(const short8*)&lA[(wr * 64 + i * 16 + ml) * BK + qa * 8];
        for (int j = 0; j < 4; ++j)
            bfr[j] = *(const short8*)&lB[(wc * 64 + j * 16 + ml) * BK + qa * 8];
        for (int i = 0; i < 4; ++i)
            for (int j = 0; j < 4; ++j)
                acc[i][j] = __builtin_amdgcn_mfma_f32_16x16x32_bf16(af[i], bfr[j], acc[i][j], 0, 0, 0);
    }

    for (int i = 0; i < 4; ++i) {
        for (int j = 0; j < 4; ++j) {
            int col = col0 + wc * 64 + j * 16 + ml;
            float bv = bias[col];
            for (int r = 0; r < 4; ++r) {
                int row = row0 + wr * 64 + i * 16 + qa * 4 + r;
                float cv = acc[i][j][r] + bv;
                if (EPI == 0) {
                    if (col < 1024) cv *= 0.125f;
                    Cb[(size_t)row * N + col] = f2bf(cv);
                } else if (EPI == 1) {
                    cv = 0.5f * cv * (1.0f + erf_inline(cv * 0.70710678118654752f));
                    Cb[(size_t)row * N + col] = f2bf(cv);
                } else {
                    cv += res[(size_t)row * N + col];
                    Cf[(size_t)row * N + col] = cv;
                }
            }
        }
    }
}

// ---------------- transpose v slice of qkv -> vT[b,h,d,s] ----------------
__global__ __launch_bounds__(256) void transpose_v(const unsigned short* __restrict__ qkv,
                                                   unsigned short* __restrict__ vT) {
    __shared__ unsigned short tile[64][72];
    int s0 = blockIdx.x * 64;
    int pair = blockIdx.y;
    int b = pair >> 4, h = pair & 15;
    int t = threadIdx.x;
    int r = t >> 2, c0 = (t & 3) * 16;
    const unsigned short* src = qkv + (size_t)(b * S_ + s0 + r) * 3072 + 2048 + h * 64 + c0;
    *(short8*)&tile[r][c0] = *(const short8*)src;
    *(short8*)&tile[r][c0 + 8] = *(const short8*)(src + 8);
    __syncthreads();
    int d = t >> 2, sc0 = (t & 3) * 16;
    unsigned short tmp[16];
    for (int i = 0; i < 16; ++i) tmp[i] = tile[sc0 + i][d];
    unsigned short* dst = vT + ((size_t)pair * 64 + d) * S_ + s0 + sc0;
    *(short8*)dst = *(const short8*)&tmp[0];
    *(short8*)(dst + 8) = *(const short8*)&tmp[8];
}

// ---------------- flash attention v3: 64 q-rows/block, online softmax ----------------
// wave w owns q-rows [qc*64 + w*16, +16) and all 64 d-cols. 8 k-chunks of 128 keys.
// K chunk staged in LDS via global_load_lds with XOR source-permute swizzle:
// LDS slot s of row holds global chunk s^(row&7). Reader wants chunk qa of key
// -> slot qa^(key&7), element offset key*64 + slot*8.  (R3 bug: slot was *64.)
__global__ __launch_bounds__(256) void attn_flash(const unsigned short* __restrict__ qkv,
                                                  const unsigned short* __restrict__ vT,
                                                  const float* __restrict__ amqf,
                                                  const float* __restrict__ negadd,
                                                  unsigned short* __restrict__ ctx) {
    __shared__ unsigned short lK[128 * 64];       // swizzled [key][slot], 16 KB
    __shared__ unsigned short lP[4][16 * 136];    // per-wave P tile, stride 136
    int qc = blockIdx.x;                          // 0..15
    int pair = blockIdx.y;
    int b = pair >> 4, h = pair & 15;
    int t = threadIdx.x, w = t >> 6, lane = t & 63;
    int qa = lane >> 4, ml = lane & 15;
    int q0 = qc * 64 + w * 16;                    // wave's first q-row

    // Q A-frags straight from global (row = q0+ml)
    const unsigned short* qrow = qkv + (size_t)(b * S_ + q0 + ml) * 3072 + h * 64;
    short8 aq0 = *(const short8*)(qrow + qa * 8);
    short8 aq1 = *(const short8*)(qrow + 32 + qa * 8);
    float amq[4];
    for (int r = 0; r < 4; ++r) amq[r] = amqf[b * S_ + q0 + qa * 4 + r];

    // staging addresses (chunk c = w*256 + i*64 + lane -> row=c>>3, slot=c&7)
    const unsigned short* ksrc[4];
    unsigned short* kdst[4];
    for (int i = 0; i < 4; ++i) {
        int c = w * 256 + i * 64 + lane;
        int row = c >> 3, slot = c & 7, e8 = slot ^ (row & 7);
        ksrc[i] = qkv + (size_t)(b * S_ + row) * 3072 + 1024 + h * 64 + e8 * 8;
        kdst[i] = lK + c * 8;
    }
    int sw0 = qa ^ (ml & 7);                // slot holding chunk qa of key (key&7 == ml&7)
    int sw1 = (qa + 4) ^ (ml & 7);          // slot holding chunk qa+4

    float m_old[4] = {-3e38f, -3e38f, -3e38f, -3e38f};
    float l[4] = {0.f, 0.f, 0.f, 0.f};
    f32x4 O[4] = {};
    unsigned short* pw = lP[w];

    for (int kc = 0; kc < 8; ++kc) {
        int kk0 = kc * 128;
        __syncthreads();                               // lK free from previous chunk
        for (int i = 0; i < 4; ++i)
            gload_lds16(ksrc[i] + (size_t)kk0 * 3072, kdst[i]);
        __syncthreads();                               // staging complete

        // scores: 8 subtiles of 16 keys
        f32x4 sacc[8];
        for (int ks = 0; ks < 8; ++ks) {
            int keyoff = (ks * 16 + ml) * 64;
            short8 bb0 = *(const short8*)(lK + keyoff + sw0 * 8);
            short8 bb1 = *(const short8*)(lK + keyoff + sw1 * 8);
            f32x4 a = {};
            a = __builtin_amdgcn_mfma_f32_16x16x32_bf16(aq0, bb0, a, 0, 0, 0);
            a = __builtin_amdgcn_mfma_f32_16x16x32_bf16(aq1, bb1, a, 0, 0, 0);
            float sb = negadd[b * S_ + kk0 + ks * 16 + ml];
            for (int r = 0; r < 4; ++r) a[r] += amq[r] + sb;
            sacc[ks] = a;
        }
        // online softmax update
        float m_new[4], alpha[4], sum[4];
        for (int r = 0; r < 4; ++r) {
            float m = m_old[r];
            for (int ks = 0; ks < 8; ++ks) m = fmaxf(m, sacc[ks][r]);
            for (int o = 8; o >= 1; o >>= 1) m = fmaxf(m, __shfl_xor(m, o, 16));
            m_new[r] = m;
            alpha[r] = __expf(m_old[r] - m);
            m_old[r] = m;
            sum[r] = 0.f;
        }
        for (int ks = 0; ks < 8; ++ks) {
            for (int r = 0; r < 4; ++r) {
                float p = __expf(sacc[ks][r] - m_new[r]);
                sum[r] += p;
                pw[(qa * 4 + r) * 136 + ks * 16 + ml] = f2bf(p);
            }
        }
        for (int r = 0; r < 4; ++r) {
            float s = sum[r];
            for (int o = 8; o >= 1; o >>= 1) s += __shfl_xor(s, o, 16);
            l[r] = l[r] * alpha[r] + s;
        }
        for (int ds = 0; ds < 4; ++ds)
            for (int r = 0; r < 4; ++r)
                O[ds][r] *= alpha[r];
        // PV: P[16x128] @ V[128x64]  (V via vT rows, contiguous in s)
        for (int ds = 0; ds < 4; ++ds) {
            const unsigned short* vtp = vT + ((size_t)pair * 64 + ds * 16 + ml) * S_ + kk0;
            for (int kst = 0; kst < 4; ++kst) {
                short8 ap = *(const short8*)(pw + ml * 136 + kst * 32 + qa * 8);
                short8 bp = *(const short8*)(vtp + kst * 32 + qa * 8);
                O[ds] = __builtin_amdgcn_mfma_f32_16x16x32_bf16(ap, bp, O[ds], 0, 0, 0);
            }
        }
    }
    // epilogue
    for (int r = 0; r < 4; ++r) {
        float inv = 1.0f / l[r];
        size_t orow = (size_t)(b * S_ + q0 + qa * 4 + r) * E_ + h * 64;
        for (int ds = 0; ds < 4; ++ds)
            ctx[orow + ds * 16 + ml] = f2bf(O[ds][r] * inv);
    }
}

// ---------------- row LayerNorm over E=1024 ----------------
template <int WRITE_BF16>
__global__ __launch_bounds__(256) void ln_kernel(const float* __restrict__ in,
                                                 const float* __restrict__ lw,
                                                 const float* __restrict__ lb,
                                                 float* __restrict__ outf,
                                                 unsigned short* __restrict__ outb) {
    int row = blockIdx.x;
    int t = threadIdx.x;
    const float* x = in + (size_t)row * E_;
    float4 v = ((const float4*)x)[t];
    float s = v.x + v.y + v.z + v.w;
    float sq = v.x * v.x + v.y * v.y + v.z * v.z + v.w * v.w;
    for (int o = 32; o >= 1; o >>= 1) {
        s += __shfl_xor(s, o, 64);
        sq += __shfl_xor(sq, o, 64);
    }
    __shared__ float red[8];
    if ((t & 63) == 0) { red[t >> 6] = s; red[4 + (t >> 6)] = sq; }
    __syncthreads();
    s = red[0] + red[1] + red[2] + red[3];
    sq = red[4] + red[5] + red[6] + red[7];
    float mu = s * (1.0f / E_);
    float var = sq * (1.0f / E_) - mu * mu;
    float rstd = rsqrtf(fmaxf(var, 0.0f) + 1e-12f);
    float4 wv = ((const float4*)lw)[t];
    float4 bv = ((const float4*)lb)[t];
    float4 o;
    o.x = (v.x - mu) * rstd * wv.x + bv.x;
    o.y = (v.y - mu) * rstd * wv.y + bv.y;
    o.z = (v.z - mu) * rstd * wv.z + bv.z;
    o.w = (v.w - mu) * rstd * wv.w + bv.w;
    ((float4*)(outf + (size_t)row * E_))[t] = o;
    if (WRITE_BF16) {
        ushort4 ob;
        ob.x = f2bf(o.x); ob.y = f2bf(o.y); ob.z = f2bf(o.z); ob.w = f2bf(o.w);
        ((ushort4*)(outb + (size_t)row * E_))[t] = ob;
    }
}

extern "C" void kernel_launch(void* const* d_in, const int* in_sizes, int n_in,
                              void* d_out, int out_size, void* d_ws, size_t ws_size,
                              hipStream_t stream) {
    const float* x        = (const float*)d_in[0];
    const int*   am       = (const int*)d_in[1];
    const int*   tt       = (const int*)d_in[2];
    const float* in_w     = (const float*)d_in[3];
    const float* in_b     = (const float*)d_in[4];
    const float* out_w    = (const float*)d_in[5];
    const float* out_b    = (const float*)d_in[6];
    const float* ln_w     = (const float*)d_in[7];
    const float* ln_b     = (const float*)d_in[8];
    const float* w_in     = (const float*)d_in[9];
    const float* b_in     = (const float*)d_in[10];
    const float* w_out    = (const float*)d_in[11];
    const float* b_out    = (const float*)d_in[12];
    float* out = (float*)d_out;

    const size_t MB = 1024 * 1024;
    char* ws = (char*)d_ws;
    unsigned short* xb    = (unsigned short*)(ws + 0);        // 16 MB (reused as hb)
    unsigned short* hb    = xb;
    unsigned short* wqkvT = (unsigned short*)(ws + 16 * MB);  // 6 MB
    unsigned short* woutT = (unsigned short*)(ws + 22 * MB);  // 2 MB
    unsigned short* winT  = (unsigned short*)(ws + 24 * MB);  // 8 MB
    unsigned short* wo2T  = (unsigned short*)(ws + 32 * MB);  // 8 MB
    unsigned short* qkvb  = (unsigned short*)(ws + 40 * MB);  // 48 MB
    unsigned short* vT    = (unsigned short*)(ws + 88 * MB);  // 16 MB
    unsigned short* ctx   = (unsigned short*)(ws + 104 * MB); // 16 MB
    float*          res1  = (float*)(ws + 120 * MB);          // 32 MB (reused for res2)
    float*          hbuf  = (float*)(ws + 152 * MB);          // 32 MB
    unsigned short* ffmid = (unsigned short*)(ws + 184 * MB); // 64 MB  -> total 248 MB
    // mask floats live in the ffmid region (unused until gemm3, attn is done by then)
    float*          amqf  = (float*)(ws + 184 * MB);          // 32 KB
    float*          negadd= (float*)(ws + 185 * MB);          // 32 KB

    // 1. cast x -> bf16; mask prep
    cast_f32_bf16<<<dim3(M_ * E_ / 1024), 256, 0, stream>>>(x, xb);
    mask_prep<<<dim3(M_ / 256), 256, 0, stream>>>(am, tt, amqf, negadd);
    // 2. transpose-cast weights
    transpose_cast<<<dim3(3 * E_ / 32, E_ / 32), 256, 0, stream>>>(in_w, wqkvT, E_, 3 * E_);
    transpose_cast<<<dim3(E_ / 32, E_ / 32), 256, 0, stream>>>(out_w, woutT, E_, E_);
    transpose_cast<<<dim3(F_ / 32, E_ / 32), 256, 0, stream>>>(w_in, winT, E_, F_);
    transpose_cast<<<dim3(E_ / 32, F_ / 32), 256, 0, stream>>>(w_out, wo2T, F_, E_);
    // 3. qkv = x @ in_proj_w + in_proj_b  (q scaled by 1/8)
    gemm_bt<0><<<dim3(3 * E_ / BN, M_ / BM), 256, 0, stream>>>(xb, wqkvT, in_b, nullptr,
                                                               qkvb, nullptr, M_, 3 * E_, E_);
    // 4. vT
    transpose_v<<<dim3(S_ / 64, B_ * H_), 256, 0, stream>>>(qkvb, vT);
    // 5. attention -> ctx
    attn_flash<<<dim3(S_ / 64, B_ * H_), 256, 0, stream>>>(qkvb, vT, amqf, negadd, ctx);
    // 6. attn_out + x  (fp32)
    gemm_bt<2><<<dim3(E_ / BN, M_ / BM), 256, 0, stream>>>(ctx, woutT, out_b, x,
                                                           nullptr, res1, M_, E_, E_);
    // 7. LN1 -> hbuf (f32) + hb (bf16)
    ln_kernel<1><<<dim3(M_), 256, 0, stream>>>(res1, ln_w, ln_b, hbuf, hb);
    // 8. ffmid = gelu(h @ w_in + b_in)
    gemm_bt<1><<<dim3(F_ / BN, M_ / BM), 256, 0, stream>>>(hb, winT, b_in, nullptr,
                                                           ffmid, nullptr, M_, F_, E_);
    // 9. ff + h (fp32)
    gemm_bt<2><<<dim3(E_ / BN, M_ / BM), 256, 0, stream>>>(ffmid, wo2T, b_out, hbuf,
                                                           nullptr, res1, M_, E_, F_);
    // 10. LN2 -> out
    ln_kernel<0><<<dim3(M_), 256, 0, stream>>>(res1, ln_w, ln_b, out, nullptr);
}